// Round 14
// baseline (460.990 us; speedup 1.0000x reference)
//
#include <hip/hip_runtime.h>
#include <hip/hip_bf16.h>

// NeRF coarse renderer — 2-ray software-pipelined block.
// Layer 2 on bf16 MFMA: rows 0-47 1-term Ah*Bh; rows 48-63 3-term
// Ah*(Bh+Bl)+Al*Bh (sample 63 feeds the alpha=1-exp(-1e10*relu(sigma)) STEP).
// Layer 3 on MFMA (wave-K-split, shared A/B k-map g(hi,e)=(e&1)*16+hi*4+(e>>1)).
// sigma_63 f32-exact via comb[wv][63][3] overwrite (same-wave DS order).
// PIPELINE (4 barriers):
//   R1: ph1(r0)
//   R2: ph2(r0) MFMA  ∥ ph1(r1) VALU
//   R3: ph2(r1) MFMA  ∥ ph3(r0)+ph4(r0)
//   R4: ph3(r1)+ph4(r1) ∥ ph5(r0)
//   R5: ph5(r1)
// => VALU and MFMA pipes busy simultaneously (r13 showed wall = VALU+MFMA sum
// with pipe-pure phases; this targets wall = max of the two).
// LDS: A0,A1 (32 KiB each, A aliases h2f after its ph2) + L0,L1 (8 KiB each,
// al3 aliases comb after its ph2) = 81920 B exactly => 2 blocks/CU.
// b2 folded into MFMA acc init. launch_bounds(512,4) => 128 VGPR cap.
//
// d_in: 0 near 1 far 2 center 3 dir 4 W1 5 b1 6 W2 7 b2 8 W3 9 b3
// d_out: [rgb (B,3) | depth (B) | weights (B,64) | sigmas_last (B)] f32
// d_ws: W2 as B-frags, bf16 hi[64K]+lo[64K].

constexpr int H  = 256;
constexpr int KS = 64;

typedef __attribute__((ext_vector_type(8))) short short8;
typedef __attribute__((ext_vector_type(4))) float f32x4;

__device__ __forceinline__ f32x4 mfma16(short8 a, short8 b, f32x4 c) {
    return __builtin_amdgcn_mfma_f32_16x16x32_bf16(a, b, c, 0, 0, 0);
}
__device__ __forceinline__ void split_bf16(float x, short& hi, short& lo) {
    __hip_bfloat16 h = __float2bfloat16(x);
    float hf = __bfloat162float(h);
    __hip_bfloat16 l = __float2bfloat16(x - hf);
    union { __hip_bfloat16 b; short s; } c1, c2;
    c1.b = h; c2.b = l;
    hi = c1.s; lo = c2.s;
}
__device__ __forceinline__ unsigned short f2bf(float x) {
    union { __hip_bfloat16 b; unsigned short s; } c;
    c.b = __float2bfloat16(x);
    return c.s;
}
__device__ __forceinline__ float bf2f(unsigned short s) {
    union { unsigned int u; float f; } c;
    c.u = ((unsigned int)s) << 16;
    return c.f;
}
__device__ __forceinline__ unsigned int pack2bf(float a, float b) {
    return (unsigned int)f2bf(a) | ((unsigned int)f2bf(b) << 16);
}

__global__ void pack_w2_kernel(const float* __restrict__ W2,
                               unsigned short* __restrict__ hi,
                               unsigned short* __restrict__ lo)
{
    const int i  = blockIdx.x * 256 + threadIdx.x;
    const int e  = i & 7;
    const int l  = (i >> 3) & 63;
    const int nt = (i >> 9) & 15;
    const int ks = i >> 13;
    const int k  = ks * 32 + (l >> 4) * 8 + e;
    const int n  = nt * 16 + (l & 15);
    short h, lw;
    split_bf16(W2[k * H + n], h, lw);
    hi[i] = (unsigned short)h;
    lo[i] = (unsigned short)lw;
}

struct SM {
    unsigned short A0[8 * 4 * 64 * 8];   // 32 KiB: r0 A-frags -> h2f(r0)
    unsigned short A1[8 * 4 * 64 * 8];   // 32 KiB: r1 A-frags -> h2f(r1)
    unsigned short L0[8 * 64 * 8];       //  8 KiB: r0 al3 -> comb0 (f32[8][64][4])
    unsigned short L1[8 * 64 * 8];       //  8 KiB: r1 al3 -> comb1
};                                       // total 81920 B

__launch_bounds__(512, 4)
__global__ void nerf_mfma_kernel(
    const float* __restrict__ g_near, const float* __restrict__ g_far,
    const float* __restrict__ g_center, const float* __restrict__ g_dir,
    const float* __restrict__ W1, const float* __restrict__ b1,
    const float* __restrict__ b2,
    const float* __restrict__ W3, const float* __restrict__ b3,
    const unsigned short* __restrict__ w2h, const unsigned short* __restrict__ w2l,
    float* __restrict__ out, int B)
{
    __shared__ __align__(16) SM sm;

    const int t    = threadIdx.x;
    const int lane = t & 63;
    const int wv   = __builtin_amdgcn_readfirstlane(t >> 6);
    const int r0   = blockIdx.x * 2;
    const int r1g  = r0 + 1;
    const int r1   = min(r1g, B - 1);          // clamp loads; stores guarded

    // ---- ray params ----
    const float nr0 = g_near[r0], fa0 = g_far[r0];
    const float nr1 = g_near[r1], fa1 = g_far[r1];
    const float c0x = g_center[r0*3+0], c0y = g_center[r0*3+1], c0z = g_center[r0*3+2];
    const float d0x = g_dir[r0*3+0],    d0y = g_dir[r0*3+1],    d0z = g_dir[r0*3+2];
    const float c1x = g_center[r1*3+0], c1y = g_center[r1*3+1], c1z = g_center[r1*3+2];
    const float d1x = g_dir[r1*3+0],    d1y = g_dir[r1*3+1],    d1z = g_dir[r1*3+2];

    // ---- per-thread column constants (shared by both rays) ----
    const int  j0 = lane & 15;
    const int  cA = wv * 32 + j0, cB = cA + 16;
    const float b2cA = b2[cA], b2cB = b2[cB];
    const float w3A = W3[cA * 4 + 3], w3B = W3[cB * 4 + 3];
    const bool lastGrp = ((lane >> 4) == 3);

    // ---- W3 B-frag, built once (k-map g(hi,e)=(e&1)*16+hi*4+(e>>1)) ----
    short8 bw3;
    {
        const int hi = lane >> 4;
        #pragma unroll
        for (int e = 0; e < 8; ++e) {
            const int k = wv * 32 + (e & 1) * 16 + hi * 4 + (e >> 1);
            bw3[e] = (short)f2bf((j0 < 4) ? W3[k * 4 + j0] : 0.0f);
        }
    }

    // ================= phase lambdas =================
    auto ph1 = [&](float nr, float fa, float cx, float cy, float cz,
                   float dx, float dy, float dz,
                   unsigned short* __restrict__ A, unsigned short* __restrict__ AL3)
    {
        const int kbase = wv * 32 + (lane >> 4) * 8;
        float w1r[3][8], b1r[8];
        #pragma unroll
        for (int c = 0; c < 3; ++c) {
            const f32x4 a = *(const f32x4*)&W1[c * H + kbase];
            const f32x4 b = *(const f32x4*)&W1[c * H + kbase + 4];
            #pragma unroll
            for (int e = 0; e < 4; ++e) { w1r[c][e] = a[e]; w1r[c][e+4] = b[e]; }
        }
        {
            const f32x4 a = *(const f32x4*)&b1[kbase];
            const f32x4 b = *(const f32x4*)&b1[kbase + 4];
            #pragma unroll
            for (int e = 0; e < 4; ++e) { b1r[e] = a[e]; b1r[e+4] = b[e]; }
        }
        const int prow = lane & 15;
        #pragma unroll
        for (int mt = 0; mt < 4; ++mt) {
            const int srow = mt * 16 + prow;
            const float uu = (float)srow * (1.0f / 63.0f);
            const float z  = nr * (1.0f - uu) + fa * uu;
            const float px = cx + z * dx, py = cy + z * dy, pz = cz + z * dz;
            float xs[8];
            #pragma unroll
            for (int e = 0; e < 8; ++e) {
                float x = fmaf(px, w1r[0][e],
                          fmaf(py, w1r[1][e],
                          fmaf(pz, w1r[2][e], b1r[e])));
                xs[e] = fmaxf(x, 0.0f);
            }
            unsigned int hw[4];
            #pragma unroll
            for (int p2 = 0; p2 < 4; ++p2) hw[p2] = pack2bf(xs[p2*2], xs[p2*2+1]);
            unsigned int* dst = (unsigned int*)&A[((wv*4+mt)*64+lane)*8];
            dst[0] = hw[0]; dst[1] = hw[1]; dst[2] = hw[2]; dst[3] = hw[3];
            if (mt == 3) {
                unsigned int lw[4];
                #pragma unroll
                for (int p2 = 0; p2 < 4; ++p2) {
                    const float l0 = xs[p2*2]   - bf2f((unsigned short)(hw[p2] & 0xffffu));
                    const float l1 = xs[p2*2+1] - bf2f((unsigned short)(hw[p2] >> 16));
                    lw[p2] = pack2bf(l0, l1);
                }
                unsigned int* dl = (unsigned int*)&AL3[(wv*64+lane)*8];
                dl[0] = lw[0]; dl[1] = lw[1]; dl[2] = lw[2]; dl[3] = lw[3];
            }
        }
    };

    auto ph2 = [&](const unsigned short* __restrict__ A,
                   const unsigned short* __restrict__ AL3,
                   f32x4 (&acc)[4][2])
    {
        const int ntg0 = wv * 2, ntg1 = ntg0 + 1;
        const short8* Bh = (const short8*)w2h;
        const short8* Bl = (const short8*)w2l;
        const short8* Ah = (const short8*)A;
        const short8* Al = (const short8*)AL3;
        #pragma unroll
        for (int ks = 0; ks < 8; ++ks) {
            const short8 b0h  = Bh[(ks * 16 + ntg0) * 64 + lane];
            const short8 b1h_ = Bh[(ks * 16 + ntg1) * 64 + lane];
            #pragma unroll
            for (int mt = 0; mt < 4; ++mt) {
                const short8 ah = Ah[(ks * 4 + mt) * 64 + lane];
                f32x4 c0 = acc[mt][0], c1 = acc[mt][1];
                c0 = mfma16(ah, b0h, c0);
                c1 = mfma16(ah, b1h_, c1);
                if (mt == 3) {
                    const short8 b0l = Bl[(ks * 16 + ntg0) * 64 + lane];
                    const short8 b1l = Bl[(ks * 16 + ntg1) * 64 + lane];
                    const short8 al  = Al[ks * 64 + lane];
                    c0 = mfma16(ah, b0l, c0);
                    c0 = mfma16(al, b0h, c0);
                    c1 = mfma16(ah, b1l, c1);
                    c1 = mfma16(al, b1h_, c1);
                }
                acc[mt][0] = c0; acc[mt][1] = c1;
            }
        }
    };

    // ph3: relu (b2 already in acc) -> bf16 h2 A-frag order (packed u32 pairs)
    auto ph3 = [&](const f32x4 (&acc)[4][2], unsigned short* __restrict__ H2F,
                   float& r63a, float& r63b)
    {
        const int rlow = (lane >> 4) * 4;
        const int hi2  = j0 >> 2;
        const int e0   = (j0 & 3) * 2;
        #pragma unroll
        for (int mt = 0; mt < 4; ++mt) {
            const f32x4 v0 = acc[mt][0], v1 = acc[mt][1];
            #pragma unroll
            for (int q = 0; q < 4; ++q) {
                const float a0 = fmaxf(v0[q], 0.0f);
                const float a1 = fmaxf(v1[q], 0.0f);
                const int l2 = (hi2 << 4) | (rlow + q);
                *(unsigned int*)&H2F[((wv*4+mt)*64 + l2)*8 + e0] = pack2bf(a0, a1);
                if (mt == 3 && q == 3) { r63a = a0; r63b = a1; }
            }
        }
    };

    // ph4: layer-3 MFMA K-split -> COMB[wv]; then f32 sigma63 overwrite
    auto ph4 = [&](const unsigned short* __restrict__ H2F,
                   float* __restrict__ COMB, float r63a, float r63b)
    {
        const int hi = lane >> 4;
        const short8* Ah2 = (const short8*)H2F;
        #pragma unroll
        for (int mt = 0; mt < 4; ++mt) {
            const short8 a = Ah2[(wv * 4 + mt) * 64 + lane];
            f32x4 d = (f32x4){0.f,0.f,0.f,0.f};
            d = mfma16(a, bw3, d);
            if (j0 < 4) {
                #pragma unroll
                for (int q = 0; q < 4; ++q)
                    COMB[(wv * 64 + mt * 16 + hi * 4 + q) * 4 + j0] = d[q];
            }
        }
        if (lastGrp) {
            float p = fmaf(r63a, w3A, r63b * w3B);
            #pragma unroll
            for (int off = 1; off < 16; off <<= 1) p += __shfl_xor(p, off, 64);
            if (j0 == 0) COMB[(wv * 64 + 63) * 4 + 3] = p;   // wins: same-wave DS order
        }
    };

    auto ph5 = [&](const float* __restrict__ COMB, float nr, float fa, int r)
    {
        if (t < KS) {
            const int s = t;
            f32x4 oo = (f32x4){0.f,0.f,0.f,0.f};
            #pragma unroll
            for (int q = 0; q < 8; ++q) {
                const f32x4 c = *(const f32x4*)&COMB[(q * 64 + s) * 4];
                oo[0] += c[0]; oo[1] += c[1]; oo[2] += c[2]; oo[3] += c[3];
            }
            const float o0 = oo[0] + b3[0];
            const float o1 = oo[1] + b3[1];
            const float o2 = oo[2] + b3[2];
            const float sigma = oo[3] + b3[3];

            const float uu = (float)s * (1.0f / 63.0f);
            const float z  = nr * (1.0f - uu) + fa * uu;
            const float u2 = (float)(s + 1) * (1.0f / 63.0f);
            const float z2 = nr * (1.0f - u2) + fa * u2;
            const float delta = (s == 63) ? 1e10f : (z2 - z);
            const float alpha = 1.0f - __expf(-delta * fmaxf(sigma, 0.0f));

            float P = 1.0f - alpha + 1e-8f;
            #pragma unroll
            for (int off = 1; off < 64; off <<= 1) {
                const float v = __shfl_up(P, off, 64);
                if (s >= off) P *= v;
            }
            float T = __shfl_up(P, 1, 64);
            if (s == 0) T = 1.0f;
            const float w = alpha * T;

            out[(size_t)B * 4 + (size_t)r * 64 + s] = w;

            float ws = w, dep = w * z, q0 = w * o0, q1 = w * o1, q2 = w * o2;
            #pragma unroll
            for (int off = 32; off > 0; off >>= 1) {
                ws  += __shfl_xor(ws,  off, 64);
                dep += __shfl_xor(dep, off, 64);
                q0  += __shfl_xor(q0,  off, 64);
                q1  += __shfl_xor(q1,  off, 64);
                q2  += __shfl_xor(q2,  off, 64);
            }
            const float sl = __shfl(sigma, 63, 64);
            if (s == 0) {
                out[(size_t)r * 3 + 0] = q0 + 1.0f - ws;
                out[(size_t)r * 3 + 1] = q1 + 1.0f - ws;
                out[(size_t)r * 3 + 2] = q2 + 1.0f - ws;
                out[(size_t)B * 3 + r] = dep;
                out[(size_t)B * 68 + r] = sl;
            }
        }
    };

    // ================= pipeline =================
    // R1
    ph1(nr0, fa0, c0x, c0y, c0z, d0x, d0y, d0z, sm.A0, sm.L0);
    __syncthreads();

    // R2: ph2(r0) MFMA ∥ ph1(r1) VALU
    f32x4 acc0[4][2];
    #pragma unroll
    for (int mt = 0; mt < 4; ++mt) {
        acc0[mt][0] = (f32x4){b2cA, b2cA, b2cA, b2cA};
        acc0[mt][1] = (f32x4){b2cB, b2cB, b2cB, b2cB};
    }
    ph2(sm.A0, sm.L0, acc0);
    ph1(nr1, fa1, c1x, c1y, c1z, d1x, d1y, d1z, sm.A1, sm.L1);
    __syncthreads();

    // R3: ph2(r1) MFMA ∥ ph3(r0)+ph4(r0)
    f32x4 acc1[4][2];
    #pragma unroll
    for (int mt = 0; mt < 4; ++mt) {
        acc1[mt][0] = (f32x4){b2cA, b2cA, b2cA, b2cA};
        acc1[mt][1] = (f32x4){b2cB, b2cB, b2cB, b2cB};
    }
    ph2(sm.A1, sm.L1, acc1);
    {
        float r63a0 = 0.f, r63b0 = 0.f;
        ph3(acc0, sm.A0, r63a0, r63b0);
        ph4(sm.A0, (float*)sm.L0, r63a0, r63b0);
    }
    __syncthreads();

    // R4: ph3(r1)+ph4(r1) ∥ ph5(r0)
    {
        float r63a1 = 0.f, r63b1 = 0.f;
        ph3(acc1, sm.A1, r63a1, r63b1);
        ph4(sm.A1, (float*)sm.L1, r63a1, r63b1);
    }
    ph5((const float*)sm.L0, nr0, fa0, r0);
    __syncthreads();

    // R5
    if (r1g < B) ph5((const float*)sm.L1, nr1, fa1, r1g);
}

extern "C" void kernel_launch(void* const* d_in, const int* in_sizes, int n_in,
                              void* d_out, int out_size, void* d_ws, size_t ws_size,
                              hipStream_t stream)
{
    const int B = in_sizes[0];
    if (ws_size < (size_t)(2 * 65536 * sizeof(unsigned short))) return;

    unsigned short* w2h = (unsigned short*)d_ws;
    unsigned short* w2l = w2h + 65536;

    pack_w2_kernel<<<256, 256, 0, stream>>>((const float*)d_in[6], w2h, w2l);

    const int grid = (B + 1) / 2;
    nerf_mfma_kernel<<<grid, 512, 0, stream>>>(
        (const float*)d_in[0], (const float*)d_in[1],
        (const float*)d_in[2], (const float*)d_in[3],
        (const float*)d_in[4], (const float*)d_in[5],
        (const float*)d_in[7],
        (const float*)d_in[8], (const float*)d_in[9],
        w2h, w2l,
        (float*)d_out, B);
}

// Round 15
// 255.514 us; speedup vs baseline: 1.8042x; 1.8042x over previous
//
#include <hip/hip_runtime.h>
#include <hip/hip_bf16.h>

// NeRF coarse renderer — 2-ray software-pipelined block, macro-inlined
// (r14 lesson: lambdas + by-ref acc arrays => scratch spill, 709 MB/dispatch).
// Layer 2 bf16 MFMA: rows 0-47 1-term Ah*Bh; rows 48-63 3-term (sigma step).
// Layer 3 MFMA wave-K-split, shared k-map g(hi,e)=(e&1)*16+hi*4+(e>>1).
// sigma_63 f32-exact via comb[wv][63][3] overwrite (same-wave DS order).
// PIPELINE (4 barriers):
//   R1: ph1(r0)
//   R2: ph2(r0)->acc0 ; ph1(r1)          (waves skew across MFMA/VALU parts)
//   R3: ph3(r0) kills acc0 ; ph2(r1)->acc1 ; ph4(r0)
//   R4: ph3(r1) ; ph4(r1) ; ph5(r0)
//   R5: ph5(r1)
// LDS: A0,A1 32 KiB (A-frags -> h2f) + L0,L1 8 KiB (al3 -> comb) = 81920 B
// => 2 blocks/CU. b2 folded into acc init. launch_bounds(512,4) => 128 VGPR cap.

constexpr int H  = 256;
constexpr int KS = 64;

typedef __attribute__((ext_vector_type(8))) short short8;
typedef __attribute__((ext_vector_type(4))) float f32x4;

__device__ __forceinline__ f32x4 mfma16(short8 a, short8 b, f32x4 c) {
    return __builtin_amdgcn_mfma_f32_16x16x32_bf16(a, b, c, 0, 0, 0);
}
__device__ __forceinline__ void split_bf16(float x, short& hi, short& lo) {
    __hip_bfloat16 h = __float2bfloat16(x);
    float hf = __bfloat162float(h);
    __hip_bfloat16 l = __float2bfloat16(x - hf);
    union { __hip_bfloat16 b; short s; } c1, c2;
    c1.b = h; c2.b = l;
    hi = c1.s; lo = c2.s;
}
__device__ __forceinline__ unsigned short f2bf(float x) {
    union { __hip_bfloat16 b; unsigned short s; } c;
    c.b = __float2bfloat16(x);
    return c.s;
}
__device__ __forceinline__ float bf2f(unsigned short s) {
    union { unsigned int u; float f; } c;
    c.u = ((unsigned int)s) << 16;
    return c.f;
}
__device__ __forceinline__ unsigned int pack2bf(float a, float b) {
    return (unsigned int)f2bf(a) | ((unsigned int)f2bf(b) << 16);
}

__global__ void pack_w2_kernel(const float* __restrict__ W2,
                               unsigned short* __restrict__ hi,
                               unsigned short* __restrict__ lo)
{
    const int i  = blockIdx.x * 256 + threadIdx.x;
    const int e  = i & 7;
    const int l  = (i >> 3) & 63;
    const int nt = (i >> 9) & 15;
    const int ks = i >> 13;
    const int k  = ks * 32 + (l >> 4) * 8 + e;
    const int n  = nt * 16 + (l & 15);
    short h, lw;
    split_bf16(W2[k * H + n], h, lw);
    hi[i] = (unsigned short)h;
    lo[i] = (unsigned short)lw;
}

struct SM {
    unsigned short A0[8 * 4 * 64 * 8];   // 32 KiB: r0 A-frags -> h2f(r0)
    unsigned short A1[8 * 4 * 64 * 8];   // 32 KiB: r1 A-frags -> h2f(r1)
    unsigned short L0[8 * 64 * 8];       //  8 KiB: r0 al3 -> comb0 f32[8][64][4]
    unsigned short L1[8 * 64 * 8];       //  8 KiB: r1 al3 -> comb1
};                                       // 81920 B

// ---------------- phase macros (textual inline; no lambdas) ----------------
#define PH1(nr_, fa_, cx_, cy_, cz_, dx_, dy_, dz_, Abuf, Lbuf)                  \
do {                                                                             \
    const int kbase = wv * 32 + (lane >> 4) * 8;                                 \
    float w1r[3][8], b1r[8];                                                     \
    _Pragma("unroll")                                                            \
    for (int c = 0; c < 3; ++c) {                                                \
        const f32x4 a_ = *(const f32x4*)&W1[c * H + kbase];                      \
        const f32x4 b_ = *(const f32x4*)&W1[c * H + kbase + 4];                  \
        _Pragma("unroll")                                                        \
        for (int e = 0; e < 4; ++e) { w1r[c][e] = a_[e]; w1r[c][e+4] = b_[e]; }  \
    }                                                                            \
    {                                                                            \
        const f32x4 a_ = *(const f32x4*)&b1[kbase];                              \
        const f32x4 b_ = *(const f32x4*)&b1[kbase + 4];                          \
        _Pragma("unroll")                                                        \
        for (int e = 0; e < 4; ++e) { b1r[e] = a_[e]; b1r[e+4] = b_[e]; }        \
    }                                                                            \
    const int prow = lane & 15;                                                  \
    _Pragma("unroll")                                                            \
    for (int mt = 0; mt < 4; ++mt) {                                             \
        const int srow = mt * 16 + prow;                                         \
        const float uu = (float)srow * (1.0f / 63.0f);                           \
        const float z  = (nr_) * (1.0f - uu) + (fa_) * uu;                       \
        const float px = (cx_) + z * (dx_), py = (cy_) + z * (dy_),              \
                    pz = (cz_) + z * (dz_);                                      \
        float xs[8];                                                             \
        _Pragma("unroll")                                                        \
        for (int e = 0; e < 8; ++e) {                                            \
            float x = fmaf(px, w1r[0][e],                                        \
                      fmaf(py, w1r[1][e],                                        \
                      fmaf(pz, w1r[2][e], b1r[e])));                             \
            xs[e] = fmaxf(x, 0.0f);                                              \
        }                                                                        \
        unsigned int hw[4];                                                      \
        _Pragma("unroll")                                                        \
        for (int p2 = 0; p2 < 4; ++p2) hw[p2] = pack2bf(xs[p2*2], xs[p2*2+1]);   \
        unsigned int* dst = (unsigned int*)&(Abuf)[((wv*4+mt)*64+lane)*8];       \
        dst[0] = hw[0]; dst[1] = hw[1]; dst[2] = hw[2]; dst[3] = hw[3];          \
        if (mt == 3) {                                                           \
            unsigned int lw[4];                                                  \
            _Pragma("unroll")                                                    \
            for (int p2 = 0; p2 < 4; ++p2) {                                     \
                const float l0 = xs[p2*2]   - bf2f((unsigned short)(hw[p2] & 0xffffu)); \
                const float l1 = xs[p2*2+1] - bf2f((unsigned short)(hw[p2] >> 16));     \
                lw[p2] = pack2bf(l0, l1);                                        \
            }                                                                    \
            unsigned int* dl = (unsigned int*)&(Lbuf)[(wv*64+lane)*8];           \
            dl[0] = lw[0]; dl[1] = lw[1]; dl[2] = lw[2]; dl[3] = lw[3];          \
        }                                                                        \
    }                                                                            \
} while (0)

#define PH2(Abuf, Lbuf, acc)                                                     \
do {                                                                             \
    const int ntg0 = wv * 2, ntg1 = ntg0 + 1;                                    \
    const short8* Bh = (const short8*)w2h;                                       \
    const short8* Bl = (const short8*)w2l;                                       \
    const short8* Ah = (const short8*)(Abuf);                                    \
    const short8* Al = (const short8*)(Lbuf);                                    \
    _Pragma("unroll 2")                                                          \
    for (int ks = 0; ks < 8; ++ks) {                                             \
        const short8 b0h  = Bh[(ks * 16 + ntg0) * 64 + lane];                    \
        const short8 b1h_ = Bh[(ks * 16 + ntg1) * 64 + lane];                    \
        _Pragma("unroll")                                                        \
        for (int mt = 0; mt < 4; ++mt) {                                         \
            const short8 ah = Ah[(ks * 4 + mt) * 64 + lane];                     \
            f32x4 c0 = acc[mt][0], c1 = acc[mt][1];                              \
            c0 = mfma16(ah, b0h, c0);                                            \
            c1 = mfma16(ah, b1h_, c1);                                           \
            if (mt == 3) {                                                       \
                const short8 b0l = Bl[(ks * 16 + ntg0) * 64 + lane];             \
                const short8 b1l = Bl[(ks * 16 + ntg1) * 64 + lane];             \
                const short8 al  = Al[ks * 64 + lane];                           \
                c0 = mfma16(ah, b0l, c0);                                        \
                c0 = mfma16(al, b0h, c0);                                        \
                c1 = mfma16(ah, b1l, c1);                                        \
                c1 = mfma16(al, b1h_, c1);                                       \
            }                                                                    \
            acc[mt][0] = c0; acc[mt][1] = c1;                                    \
        }                                                                        \
    }                                                                            \
} while (0)

#define PH3(acc, H2F, r63a_, r63b_)                                              \
do {                                                                             \
    const int rlow = (lane >> 4) * 4;                                            \
    const int hi2  = j0 >> 2;                                                    \
    const int e0   = (j0 & 3) * 2;                                               \
    _Pragma("unroll")                                                            \
    for (int mt = 0; mt < 4; ++mt) {                                             \
        const f32x4 v0 = acc[mt][0], v1 = acc[mt][1];                            \
        _Pragma("unroll")                                                        \
        for (int q = 0; q < 4; ++q) {                                            \
            const float a0 = fmaxf(v0[q], 0.0f);                                 \
            const float a1 = fmaxf(v1[q], 0.0f);                                 \
            const int l2 = (hi2 << 4) | (rlow + q);                              \
            *(unsigned int*)&(H2F)[((wv*4+mt)*64 + l2)*8 + e0] = pack2bf(a0, a1);\
            if (mt == 3 && q == 3) { r63a_ = a0; r63b_ = a1; }                   \
        }                                                                        \
    }                                                                            \
} while (0)

#define PH4(H2F, COMB, r63a_, r63b_)                                             \
do {                                                                             \
    const int hi = lane >> 4;                                                    \
    const short8* Ah2 = (const short8*)(H2F);                                    \
    _Pragma("unroll")                                                            \
    for (int mt = 0; mt < 4; ++mt) {                                             \
        const short8 a_ = Ah2[(wv * 4 + mt) * 64 + lane];                        \
        f32x4 d = (f32x4){0.f,0.f,0.f,0.f};                                      \
        d = mfma16(a_, bw3, d);                                                  \
        if (j0 < 4) {                                                            \
            _Pragma("unroll")                                                    \
            for (int q = 0; q < 4; ++q)                                          \
                (COMB)[(wv * 64 + mt * 16 + hi * 4 + q) * 4 + j0] = d[q];        \
        }                                                                        \
    }                                                                            \
    if (lastGrp) {                                                               \
        float p = fmaf(r63a_, w3A, r63b_ * w3B);                                 \
        _Pragma("unroll")                                                        \
        for (int off = 1; off < 16; off <<= 1) p += __shfl_xor(p, off, 64);      \
        if (j0 == 0) (COMB)[(wv * 64 + 63) * 4 + 3] = p;                         \
    }                                                                            \
} while (0)

#define PH5(COMB, nr_, fa_, r_)                                                  \
do {                                                                             \
    if (t < KS) {                                                                \
        const int s = t;                                                         \
        f32x4 oo = (f32x4){0.f,0.f,0.f,0.f};                                     \
        _Pragma("unroll")                                                        \
        for (int q = 0; q < 8; ++q) {                                            \
            const f32x4 c_ = *(const f32x4*)&(COMB)[(q * 64 + s) * 4];           \
            oo[0] += c_[0]; oo[1] += c_[1]; oo[2] += c_[2]; oo[3] += c_[3];      \
        }                                                                        \
        const float o0 = oo[0] + b3[0];                                          \
        const float o1 = oo[1] + b3[1];                                          \
        const float o2 = oo[2] + b3[2];                                          \
        const float sigma = oo[3] + b3[3];                                       \
        const float uu = (float)s * (1.0f / 63.0f);                              \
        const float z  = (nr_) * (1.0f - uu) + (fa_) * uu;                       \
        const float u2 = (float)(s + 1) * (1.0f / 63.0f);                        \
        const float z2 = (nr_) * (1.0f - u2) + (fa_) * u2;                       \
        const float delta = (s == 63) ? 1e10f : (z2 - z);                        \
        const float alpha = 1.0f - __expf(-delta * fmaxf(sigma, 0.0f));          \
        float P = 1.0f - alpha + 1e-8f;                                          \
        _Pragma("unroll")                                                        \
        for (int off = 1; off < 64; off <<= 1) {                                 \
            const float v_ = __shfl_up(P, off, 64);                              \
            if (s >= off) P *= v_;                                               \
        }                                                                        \
        float T = __shfl_up(P, 1, 64);                                           \
        if (s == 0) T = 1.0f;                                                    \
        const float w_ = alpha * T;                                              \
        out[(size_t)B * 4 + (size_t)(r_) * 64 + s] = w_;                         \
        float ws = w_, dep = w_ * z, q0 = w_ * o0, q1 = w_ * o1, q2 = w_ * o2;   \
        _Pragma("unroll")                                                        \
        for (int off = 32; off > 0; off >>= 1) {                                 \
            ws  += __shfl_xor(ws,  off, 64);                                     \
            dep += __shfl_xor(dep, off, 64);                                     \
            q0  += __shfl_xor(q0,  off, 64);                                     \
            q1  += __shfl_xor(q1,  off, 64);                                     \
            q2  += __shfl_xor(q2,  off, 64);                                     \
        }                                                                        \
        const float sl = __shfl(sigma, 63, 64);                                  \
        if (s == 0) {                                                            \
            out[(size_t)(r_) * 3 + 0] = q0 + 1.0f - ws;                          \
            out[(size_t)(r_) * 3 + 1] = q1 + 1.0f - ws;                          \
            out[(size_t)(r_) * 3 + 2] = q2 + 1.0f - ws;                          \
            out[(size_t)B * 3 + (r_)] = dep;                                     \
            out[(size_t)B * 68 + (r_)] = sl;                                     \
        }                                                                        \
    }                                                                            \
} while (0)

__launch_bounds__(512, 4)
__global__ void nerf_mfma_kernel(
    const float* __restrict__ g_near, const float* __restrict__ g_far,
    const float* __restrict__ g_center, const float* __restrict__ g_dir,
    const float* __restrict__ W1, const float* __restrict__ b1,
    const float* __restrict__ b2,
    const float* __restrict__ W3, const float* __restrict__ b3,
    const unsigned short* __restrict__ w2h, const unsigned short* __restrict__ w2l,
    float* __restrict__ out, int B)
{
    __shared__ __align__(16) SM sm;

    const int t    = threadIdx.x;
    const int lane = t & 63;
    const int wv   = __builtin_amdgcn_readfirstlane(t >> 6);
    const int r0   = blockIdx.x * 2;
    const int r1g  = r0 + 1;
    const int r1   = min(r1g, B - 1);

    // ---- ray params ----
    const float nr0 = g_near[r0], fa0 = g_far[r0];
    const float nr1 = g_near[r1], fa1 = g_far[r1];
    const float c0x = g_center[r0*3+0], c0y = g_center[r0*3+1], c0z = g_center[r0*3+2];
    const float d0x = g_dir[r0*3+0],    d0y = g_dir[r0*3+1],    d0z = g_dir[r0*3+2];
    const float c1x = g_center[r1*3+0], c1y = g_center[r1*3+1], c1z = g_center[r1*3+2];
    const float d1x = g_dir[r1*3+0],    d1y = g_dir[r1*3+1],    d1z = g_dir[r1*3+2];

    // ---- per-thread constants ----
    const int  j0 = lane & 15;
    const int  cA = wv * 32 + j0, cB = cA + 16;
    const float b2cA = b2[cA], b2cB = b2[cB];
    const float w3A = W3[cA * 4 + 3], w3B = W3[cB * 4 + 3];
    const bool lastGrp = ((lane >> 4) == 3);

    // W3 B-frag, built once (k-map g(hi,e)=(e&1)*16+hi*4+(e>>1))
    short8 bw3;
    {
        const int hi = lane >> 4;
        #pragma unroll
        for (int e = 0; e < 8; ++e) {
            const int k = wv * 32 + (e & 1) * 16 + hi * 4 + (e >> 1);
            bw3[e] = (short)f2bf((j0 < 4) ? W3[k * 4 + j0] : 0.0f);
        }
    }

    // ================= pipeline =================
    // R1
    PH1(nr0, fa0, c0x, c0y, c0z, d0x, d0y, d0z, sm.A0, sm.L0);
    __syncthreads();

    // R2: ph2(r0) MFMA ; ph1(r1) VALU   (waves skew across the two parts)
    f32x4 acc0[4][2];
    #pragma unroll
    for (int mt = 0; mt < 4; ++mt) {
        acc0[mt][0] = (f32x4){b2cA, b2cA, b2cA, b2cA};
        acc0[mt][1] = (f32x4){b2cB, b2cB, b2cB, b2cB};
    }
    PH2(sm.A0, sm.L0, acc0);
    PH1(nr1, fa1, c1x, c1y, c1z, d1x, d1y, d1z, sm.A1, sm.L1);
    __syncthreads();

    // R3: ph3(r0) kills acc0 ; ph2(r1)->acc1 ; ph4(r0)
    float r63a0 = 0.f, r63b0 = 0.f;
    PH3(acc0, sm.A0, r63a0, r63b0);
    f32x4 acc1[4][2];
    #pragma unroll
    for (int mt = 0; mt < 4; ++mt) {
        acc1[mt][0] = (f32x4){b2cA, b2cA, b2cA, b2cA};
        acc1[mt][1] = (f32x4){b2cB, b2cB, b2cB, b2cB};
    }
    PH2(sm.A1, sm.L1, acc1);
    PH4(sm.A0, (float*)sm.L0, r63a0, r63b0);
    __syncthreads();

    // R4: ph3(r1) ; ph4(r1) ; ph5(r0)
    {
        float r63a1 = 0.f, r63b1 = 0.f;
        PH3(acc1, sm.A1, r63a1, r63b1);
        PH4(sm.A1, (float*)sm.L1, r63a1, r63b1);
    }
    PH5((const float*)sm.L0, nr0, fa0, r0);
    __syncthreads();

    // R5
    if (r1g < B) PH5((const float*)sm.L1, nr1, fa1, r1g);
}

extern "C" void kernel_launch(void* const* d_in, const int* in_sizes, int n_in,
                              void* d_out, int out_size, void* d_ws, size_t ws_size,
                              hipStream_t stream)
{
    const int B = in_sizes[0];
    if (ws_size < (size_t)(2 * 65536 * sizeof(unsigned short))) return;

    unsigned short* w2h = (unsigned short*)d_ws;
    unsigned short* w2l = w2h + 65536;

    pack_w2_kernel<<<256, 256, 0, stream>>>((const float*)d_in[6], w2h, w2l);

    const int grid = (B + 1) / 2;
    nerf_mfma_kernel<<<grid, 512, 0, stream>>>(
        (const float*)d_in[0], (const float*)d_in[1],
        (const float*)d_in[2], (const float*)d_in[3],
        (const float*)d_in[4], (const float*)d_in[5],
        (const float*)d_in[7],
        (const float*)d_in[8], (const float*)d_in[9],
        w2h, w2l,
        (float*)d_out, B);
}